// Round 6
// baseline (665.286 us; speedup 1.0000x reference)
//
#include <hip/hip_runtime.h>
#include <hip/hip_bf16.h>

#define NN 50000
#define NE 800000
#define NT_E 12500      // 800000 / 64
#define GRID_E 1024
#define NBLK_SCAN 196   // ceil(50000/256)

typedef __attribute__((ext_vector_type(8))) short bf16x8;
typedef __attribute__((ext_vector_type(4))) float f32x4;
typedef __attribute__((ext_vector_type(2))) float f32x2;
typedef __attribute__((ext_vector_type(8))) unsigned short u16x8;
typedef __attribute__((ext_vector_type(2))) unsigned short u16x2;

__device__ __forceinline__ unsigned short f2bf(float f) {
    union { float f; unsigned u; } v; v.f = f;
    unsigned r = v.u + 0x7FFFu + ((v.u >> 16) & 1u);   // RNE
    return (unsigned short)(r >> 16);
}
__device__ __forceinline__ float bf2f(unsigned short h) {
    union { unsigned u; float f; } v; v.u = ((unsigned)h) << 16;
    return v.f;
}
__device__ __forceinline__ f32x4 mfma16(bf16x8 a, bf16x8 b, f32x4 c) {
    return __builtin_amdgcn_mfma_f32_16x16x32_bf16(a, b, c, 0, 0, 0);
}
// barrier WITHOUT vmcnt drain: cross-thread comm is via LDS only, so
// lgkmcnt(0)+s_barrier suffices; global loads/stores stay in flight.
__device__ __forceinline__ void syncl() {
    asm volatile("s_waitcnt lgkmcnt(0)\n\ts_barrier" ::: "memory");
}

__device__ __forceinline__ void load_wfrags(const unsigned short* __restrict__ Wb,
                                            int wv, int lane, bf16x8 (&wf)[4][2]) {
#pragma unroll
    for (int kk = 0; kk < 4; ++kk)
#pragma unroll
        for (int j = 0; j < 2; ++j) {
            int row = 32 * wv + 16 * j + (lane & 15);
            int col = 32 * kk + 8 * (lane >> 4);
            wf[kk][j] = *(const bf16x8*)(Wb + row * 128 + col);
        }
}

__device__ __forceinline__ void zero_acc(f32x4 (&acc)[4][2]) {
#pragma unroll
    for (int mt = 0; mt < 4; ++mt)
#pragma unroll
        for (int j = 0; j < 2; ++j) {
            f32x4 z = {0.f, 0.f, 0.f, 0.f};
            acc[mt][j] = z;
        }
}

__device__ __forceinline__ void gemm64(const unsigned short* __restrict__ X,
                                       const bf16x8 (&wf)[4][2], f32x4 (&acc)[4][2], int lane) {
#pragma unroll
    for (int kk = 0; kk < 4; ++kk) {
        bf16x8 a[4];
#pragma unroll
        for (int mt = 0; mt < 4; ++mt) {
            int row = mt * 16 + (lane & 15);
            a[mt] = *(const bf16x8*)(X + row * 136 + kk * 32 + 8 * (lane >> 4));
        }
#pragma unroll
        for (int mt = 0; mt < 4; ++mt) {
            acc[mt][0] = mfma16(a[mt], wf[kk][0], acc[mt][0]);
            acc[mt][1] = mfma16(a[mt], wf[kk][1], acc[mt][1]);
        }
    }
}

__device__ __forceinline__ void epi_lds(unsigned short* __restrict__ Xo,
                                        const f32x4 (&acc)[4][2],
                                        float bb0, float bb1, int c0, int rbase) {
#pragma unroll
    for (int mt = 0; mt < 4; ++mt)
#pragma unroll
        for (int r = 0; r < 4; ++r) {
            int row = mt * 16 + rbase + r;
            Xo[row * 136 + c0]      = f2bf(fmaxf(acc[mt][0][r] + bb0, 0.f));
            Xo[row * 136 + c0 + 16] = f2bf(fmaxf(acc[mt][1][r] + bb1, 0.f));
        }
}

// epilogue WITHOUT relu: e_emb + b3 -> bf16 LDS tile
__device__ __forceinline__ void epi_lds_norelu(unsigned short* __restrict__ Xo,
                                               const f32x4 (&acc)[4][2],
                                               float bb0, float bb1, int c0, int rbase) {
#pragma unroll
    for (int mt = 0; mt < 4; ++mt)
#pragma unroll
        for (int r = 0; r < 4; ++r) {
            int row = mt * 16 + rbase + r;
            Xo[row * 136 + c0]      = f2bf(acc[mt][0][r] + bb0);
            Xo[row * 136 + c0 + 16] = f2bf(acc[mt][1][r] + bb1);
        }
}

__device__ __forceinline__ void stage_f32row(unsigned short* __restrict__ Xrow,
                                             const f32x4* __restrict__ p) {
#pragma unroll
    for (int i = 0; i < 4; ++i) {
        f32x4 lo = p[2 * i], hi = p[2 * i + 1];
        unsigned short tmp[8];
#pragma unroll
        for (int j = 0; j < 4; ++j) { tmp[j] = f2bf(lo[j]); tmp[4 + j] = f2bf(hi[j]); }
        *(u16x8*)(Xrow + i * 8) = *(u16x8*)tmp;
    }
}

// ================= convert 9 DxD fp32 weights to bf16 =================
__global__ void k_wconv(const float* w0, const float* w1, const float* w2,
                        const float* w3, const float* w4, const float* w5,
                        const float* w6, const float* w7, const float* w8,
                        unsigned short* out) {
    const float* ws[9] = {w0, w1, w2, w3, w4, w5, w6, w7, w8};
    int m = blockIdx.x >> 2;
    int part = blockIdx.x & 3;
    const float* w = ws[m] + part * 4096 + threadIdx.x * 16;
    unsigned short* o = out + m * 16384 + part * 4096 + threadIdx.x * 16;
    float f[16];
#pragma unroll
    for (int i = 0; i < 4; ++i) *(f32x4*)(f + 4 * i) = ((const f32x4*)w)[i];
    unsigned short tmp[16];
#pragma unroll
    for (int i = 0; i < 16; ++i) tmp[i] = f2bf(f[i]);
    ((u16x8*)o)[0] = *(u16x8*)tmp;
    ((u16x8*)o)[1] = *(u16x8*)(tmp + 8);
}

// ================= sort: hist -> 3-kernel scan -> position =================
__global__ void k_hist(const int* __restrict__ dst, int* __restrict__ cnt) {
    int i = blockIdx.x * 256 + threadIdx.x;
    if (i < NE) atomicAdd(&cnt[dst[i]], 1);
}

__global__ void k_scan1(const int* __restrict__ c, int* __restrict__ bsum) {
    __shared__ int red[256];
    int i = blockIdx.x * 256 + threadIdx.x;
    red[threadIdx.x] = (i < NN) ? c[i] : 0;
    __syncthreads();
    for (int off = 128; off > 0; off >>= 1) {
        if (threadIdx.x < off) red[threadIdx.x] += red[threadIdx.x + off];
        __syncthreads();
    }
    if (threadIdx.x == 0) bsum[blockIdx.x] = red[0];
}

__global__ void k_scan2(int* __restrict__ bsum) {   // 1 block, 256 threads
    __shared__ int s[256];
    int t = threadIdx.x;
    s[t] = (t < NBLK_SCAN) ? bsum[t] : 0;
    __syncthreads();
    for (int off = 1; off < 256; off <<= 1) {
        int v = (t >= off) ? s[t - off] : 0;
        __syncthreads();
        s[t] += v;
        __syncthreads();
    }
    if (t < NBLK_SCAN) bsum[t] = (t == 0) ? 0 : s[t - 1];
}

__global__ void k_scan3(int* __restrict__ cnt, const int* __restrict__ bsum,
                        int* __restrict__ rowptr) {
    __shared__ int s[256];
    int t = threadIdx.x;
    int i = blockIdx.x * 256 + t;
    int v = (i < NN) ? cnt[i] : 0;
    s[t] = v;
    __syncthreads();
    for (int off = 1; off < 256; off <<= 1) {
        int x = (t >= off) ? s[t - off] : 0;
        __syncthreads();
        s[t] += x;
        __syncthreads();
    }
    int excl = bsum[blockIdx.x] + s[t] - v;
    if (i < NN) { rowptr[i] = excl; cnt[i] = excl; }   // cnt becomes cursor
    if (i == 0) rowptr[NN] = NE;
}

__global__ void k_pos(const int* __restrict__ dst, int* __restrict__ cursor,
                      int* __restrict__ pos) {
    int i = blockIdx.x * 256 + threadIdx.x;
    if (i < NE) pos[i] = atomicAdd(&cursor[dst[i]], 1);
}

// ================= node pre: AH = [Asrc row | Hb row], Adst =================
__global__ __launch_bounds__(256, 3)
void k_nodepre(const float* __restrict__ h,
               const unsigned short* __restrict__ Wb,
               const float* __restrict__ bsrc, const float* __restrict__ bdst,
               unsigned short* __restrict__ AH, unsigned short* __restrict__ Adst) {
    __shared__ unsigned short X[64 * 136];
    int tid = threadIdx.x, lane = tid & 63, wv = tid >> 6;
    int n0 = blockIdx.x * 64;
    {
        int row = tid >> 2, q = tid & 3;
        int n = n0 + row;
        if (n < NN) {
            unsigned short tmp[32];
            const f32x4* hp = (const f32x4*)(h + (size_t)n * 128 + q * 32);
#pragma unroll
            for (int i = 0; i < 8; ++i) {
                f32x4 v = hp[i];
#pragma unroll
                for (int j = 0; j < 4; ++j) tmp[i * 4 + j] = f2bf(v[j]);
            }
#pragma unroll
            for (int i = 0; i < 4; ++i)
                *(u16x8*)(X + row * 136 + q * 32 + i * 8) = *(u16x8*)(tmp + i * 8);
            u16x8* hb = (u16x8*)(AH + (size_t)n * 256 + 128 + q * 32);
#pragma unroll
            for (int i = 0; i < 4; ++i) hb[i] = *(u16x8*)(tmp + i * 8);
        } else {
            u16x8 z = {0, 0, 0, 0, 0, 0, 0, 0};
#pragma unroll
            for (int i = 0; i < 4; ++i) *(u16x8*)(X + row * 136 + q * 32 + i * 8) = z;
        }
    }
    __syncthreads();

    bf16x8 wfS[4][2], wfD[4][2];
    load_wfrags(Wb, wv, lane, wfS);
    load_wfrags(Wb + 16384, wv, lane, wfD);
    f32x4 accS[4][2], accD[4][2];
    zero_acc(accS); zero_acc(accD);
    gemm64(X, wfS, accS, lane);
    gemm64(X, wfD, accD, lane);

    int c0 = 32 * wv + (lane & 15);
    float bs0 = bsrc[c0], bs1 = bsrc[c0 + 16];
    float bd0 = bdst[c0], bd1 = bdst[c0 + 16];
    int rbase = (lane >> 4) * 4;
#pragma unroll
    for (int mt = 0; mt < 4; ++mt)
#pragma unroll
        for (int r = 0; r < 4; ++r) {
            int n = n0 + mt * 16 + rbase + r;
            if (n < NN) {
                AH[(size_t)n * 256 + c0]        = f2bf(accS[mt][0][r] + bs0);
                AH[(size_t)n * 256 + c0 + 16]   = f2bf(accS[mt][1][r] + bs1);
                Adst[(size_t)n * 128 + c0]      = f2bf(accD[mt][0][r] + bd0);
                Adst[(size_t)n * 128 + c0 + 16] = f2bf(accD[mt][1][r] + bd1);
            }
        }
}

// ===== edge MLP: wf1/wf2 resident, h-in-regs, 35KB LDS (4 blk/CU), Mbuf scatter
__global__ __launch_bounds__(256, 4)
void k_edgeB(const float* __restrict__ ef,
             const int* __restrict__ src, const int* __restrict__ dst,
             const int* __restrict__ pos,
             const unsigned short* __restrict__ AH,
             const unsigned short* __restrict__ Adst,
             const unsigned short* __restrict__ Wb,
             const float* __restrict__ b1, const float* __restrict__ b2,
             const float* __restrict__ b3,
             unsigned short* __restrict__ Mbuf) {
    __shared__ __align__(16) char sh[35072];
    unsigned short* X0 = (unsigned short*)sh;             // [64][136]
    unsigned short* X1 = (unsigned short*)(sh + 17408);   // [64][136]
    int*         posarr = (int*)(sh + 34816);             // [64]

    int tid = threadIdx.x, lane = tid & 63, wv = tid >> 6;

    // wf1/wf2 resident across the loop (the R4-vs-R5 A/B winner);
    // only wf3 reloads per tile.
    bf16x8 wf1[4][2], wf2[4][2];
    load_wfrags(Wb + 2 * 16384, wv, lane, wf1);   // Wphi1
    load_wfrags(Wb + 3 * 16384, wv, lane, wf2);   // Wphi2

    int c0 = 32 * wv + (lane & 15);
    float b1_0 = b1[c0], b1_1 = b1[c0 + 16];
    float b2_0 = b2[c0], b2_1 = b2[c0 + 16];
    float b3_0 = b3[c0], b3_1 = b3[c0 + 16];
    int rbase = (lane >> 4) * 4;
    int srow = tid >> 2, q = tid & 3;

    // contiguous chunk per block: ef stream stays sequential per block
    int b = blockIdx.x, nb = gridDim.x;
    int qt = NT_E / nb, rt = NT_E % nb;
    int t0 = (b < rt) ? b * (qt + 1) : rt * (qt + 1) + (b - rt) * qt;
    int t1 = t0 + ((b < rt) ? qt + 1 : qt);

    for (int t = t0; t < t1; ++t) {
        int e0 = t * 64;
        u16x8 hbr[4];                          // h_src slice, stays in regs
        syncl();                               // prev store-phase LDS reads done
        {   // stage: X0 = relu(ef + AH.a[src] + Adst[dst]); hbr = AH.h[src]
            int e = e0 + srow;
            int s = src[e], d = dst[e];
            if (q == 0) posarr[srow] = pos[e];
            const f32x4* ep = (const f32x4*)(ef + (size_t)e * 128 + q * 32);
            const u16x8* ap = (const u16x8*)(AH + (size_t)s * 256 + q * 32);
            const u16x8* hp = (const u16x8*)(AH + (size_t)s * 256 + 128 + q * 32);
            const u16x8* dp = (const u16x8*)(Adst + (size_t)d * 128 + q * 32);
#pragma unroll
            for (int i = 0; i < 4; ++i) {
                u16x8 a8 = ap[i], d8 = dp[i];
                hbr[i] = hp[i];
                f32x4 lo = ep[2 * i], hi = ep[2 * i + 1];
                unsigned short o[8];
#pragma unroll
                for (int j = 0; j < 8; ++j) {
                    float evv = (j < 4) ? lo[j] : hi[j - 4];
                    float v = evv + bf2f((unsigned short)a8[j]) + bf2f((unsigned short)d8[j]);
                    o[j] = f2bf(fmaxf(v, 0.f));
                }
                *(u16x8*)(X0 + srow * 136 + q * 32 + i * 8) = *(u16x8*)o;
            }
        }
        syncl();                               // X0/posarr visible
        f32x4 acc[4][2];
        zero_acc(acc);
        gemm64(X0, wf1, acc, lane);
        syncl();                               // X0 reads done
        epi_lds(X1, acc, b1_0, b1_1, c0, rbase);
        syncl();                               // X1 ready
        zero_acc(acc);
        gemm64(X1, wf2, acc, lane);
        epi_lds(X0, acc, b2_0, b2_1, c0, rbase);
        syncl();                               // X0 ready (X1 reads also done)
        {
            bf16x8 wf3[4][2];
            load_wfrags(Wb + 4 * 16384, wv, lane, wf3);   // Wphi3 (L2-hot)
            zero_acc(acc);
            gemm64(X0, wf3, acc, lane);
        }
        syncl();                               // X1 free (gemm2 reads long done)
        epi_lds_norelu(X1, acc, b3_0, b3_1, c0, rbase);  // X1 = e_emb + b3 (bf16)
        syncl();                               // X1 ready
        // m = h_src * e_emb in staging layout; 64B store per thread to Mbuf
        {
            int posr = posarr[srow];
            unsigned short* mp = Mbuf + (size_t)posr * 128 + q * 32;
#pragma unroll
            for (int i = 0; i < 4; ++i) {
                u16x8 ev = *(const u16x8*)(X1 + srow * 136 + q * 32 + i * 8);
                u16x8 o;
#pragma unroll
                for (int j = 0; j < 8; ++j)
                    o[j] = f2bf(bf2f((unsigned short)ev[j]) * bf2f((unsigned short)hbr[i][j]));
                *(u16x8*)(mp + i * 8) = o;
            }
        }
    }
}

// ===== fused aggregate + node output (primary path) =====
__global__ __launch_bounds__(256, 3)
void k_nodeoutF(const unsigned short* __restrict__ AH,
                const unsigned short* __restrict__ Mbuf,
                const int* __restrict__ rowptr,
                const unsigned short* __restrict__ Wb,
                const float* __restrict__ bpd, const float* __restrict__ bpu,
                const float* __restrict__ bt1, const float* __restrict__ bt2,
                float* __restrict__ out) {
    __shared__ unsigned short Xh[64 * 136];
    __shared__ unsigned short Xa[64 * 136];
    int tid = threadIdx.x, lane = tid & 63, wv = tid >> 6;
    int n0 = blockIdx.x * 64;
    {   // stage Xh = AH.h
        int row = tid >> 2, q = tid & 3;
        int n = n0 + row;
        if (n < NN) {
            const u16x8* hp = (const u16x8*)(AH + (size_t)n * 256 + 128 + q * 32);
#pragma unroll
            for (int i = 0; i < 4; ++i)
                *(u16x8*)(Xh + row * 136 + q * 32 + i * 8) = hp[i];
        } else {
            u16x8 z = {0, 0, 0, 0, 0, 0, 0, 0};
#pragma unroll
            for (int i = 0; i < 4; ++i)
                *(u16x8*)(Xh + row * 136 + q * 32 + i * 8) = z;
        }
    }
    {   // fused agg: one node per wave-iteration, sequential Mbuf rows
#pragma unroll 1
        for (int it = 0; it < 16; ++it) {
            int row = wv * 16 + it;
            int n = n0 + row;
            float a0 = 0.f, a1 = 0.f;
            if (n < NN) {
                int j0 = rowptr[n], j1 = rowptr[n + 1];
                int j = j0;
                for (; j + 3 < j1; j += 4) {
                    u16x2 v0 = *(const u16x2*)(Mbuf + (size_t)j * 128 + lane * 2);
                    u16x2 v1 = *(const u16x2*)(Mbuf + (size_t)(j + 1) * 128 + lane * 2);
                    u16x2 v2 = *(const u16x2*)(Mbuf + (size_t)(j + 2) * 128 + lane * 2);
                    u16x2 v3 = *(const u16x2*)(Mbuf + (size_t)(j + 3) * 128 + lane * 2);
                    a0 += bf2f(v0[0]) + bf2f(v1[0]) + bf2f(v2[0]) + bf2f(v3[0]);
                    a1 += bf2f(v0[1]) + bf2f(v1[1]) + bf2f(v2[1]) + bf2f(v3[1]);
                }
                for (; j < j1; ++j) {
                    u16x2 v = *(const u16x2*)(Mbuf + (size_t)j * 128 + lane * 2);
                    a0 += bf2f(v[0]); a1 += bf2f(v[1]);
                }
            }
            Xa[row * 136 + lane * 2]     = f2bf(a0);
            Xa[row * 136 + lane * 2 + 1] = f2bf(a1);
        }
    }
    __syncthreads();
    bf16x8 wfa[4][2], wfb[4][2];
    load_wfrags(Wb + 5 * 16384, wv, lane, wfa);   // Wpd
    load_wfrags(Wb + 6 * 16384, wv, lane, wfb);   // Wpu
    int c0 = 32 * wv + (lane & 15);
    int rbase = (lane >> 4) * 4;
    f32x4 acc[4][2];
    zero_acc(acc);
    gemm64(Xh, wfa, acc, lane);
    gemm64(Xa, wfb, acc, lane);
    float bb0 = bpd[c0] + bpu[c0], bb1 = bpd[c0 + 16] + bpu[c0 + 16];
    __syncthreads();
    epi_lds(Xh, acc, bb0, bb1, c0, rbase);
    __syncthreads();
    load_wfrags(Wb + 7 * 16384, wv, lane, wfa);   // Wth1
    zero_acc(acc);
    gemm64(Xh, wfa, acc, lane);
    float b10 = bt1[c0], b11 = bt1[c0 + 16];
    __syncthreads();
    epi_lds(Xa, acc, b10, b11, c0, rbase);
    __syncthreads();
    load_wfrags(Wb + 8 * 16384, wv, lane, wfb);   // Wth2
    zero_acc(acc);
    gemm64(Xa, wfb, acc, lane);
    float b20 = bt2[c0], b21 = bt2[c0 + 16];
#pragma unroll
    for (int mt = 0; mt < 4; ++mt)
#pragma unroll
        for (int r = 0; r < 4; ++r) {
            int n = n0 + mt * 16 + rbase + r;
            if (n < NN) {
                out[(size_t)n * 128 + c0]      = acc[mt][0][r] + b20;
                out[(size_t)n * 128 + c0 + 16] = acc[mt][1][r] + b21;
            }
        }
}

// ============ fallback edge kernel (direct atomics, small-ws path) ============
__global__ __launch_bounds__(256, 2)
void k_edge_atomic(const float* __restrict__ ef,
                   const int* __restrict__ src, const int* __restrict__ dst,
                   const unsigned short* __restrict__ AH,
                   const unsigned short* __restrict__ Adst,
                   const unsigned short* __restrict__ Wb,
                   const float* __restrict__ b1, const float* __restrict__ b2,
                   const float* __restrict__ b3,
                   float* __restrict__ agg) {
    __shared__ unsigned short X0[64 * 136];
    __shared__ unsigned short X1[64 * 136];
    __shared__ unsigned short Hs[64 * 136];
    __shared__ int doff_lds[64];

    int tid = threadIdx.x, lane = tid & 63, wv = tid >> 6;
    bf16x8 wf1[4][2], wf2[4][2], wf3[4][2];
    load_wfrags(Wb + 2 * 16384, wv, lane, wf1);
    load_wfrags(Wb + 3 * 16384, wv, lane, wf2);
    load_wfrags(Wb + 4 * 16384, wv, lane, wf3);

    int c0 = 32 * wv + (lane & 15);
    float b1_0 = b1[c0], b1_1 = b1[c0 + 16];
    float b2_0 = b2[c0], b2_1 = b2[c0 + 16];
    float b3_0 = b3[c0], b3_1 = b3[c0 + 16];
    int rbase = (lane >> 4) * 4;
    int srow = tid >> 2, q = tid & 3;

    for (int t = blockIdx.x; t < NT_E; t += gridDim.x) {
        int e0 = t * 64;
        __syncthreads();
        {
            int e = e0 + srow;
            int s = src[e], d = dst[e];
            if (q == 0) doff_lds[srow] = d * 128;
            const f32x4* ep = (const f32x4*)(ef + (size_t)e * 128 + q * 32);
            const u16x8* ap = (const u16x8*)(AH + (size_t)s * 256 + q * 32);
            const u16x8* hp = (const u16x8*)(AH + (size_t)s * 256 + 128 + q * 32);
            const u16x8* dp = (const u16x8*)(Adst + (size_t)d * 128 + q * 32);
#pragma unroll
            for (int i = 0; i < 4; ++i) {
                u16x8 a8 = ap[i], d8 = dp[i], h8 = hp[i];
                f32x4 lo = ep[2 * i], hi = ep[2 * i + 1];
                unsigned short o[8];
#pragma unroll
                for (int j = 0; j < 8; ++j) {
                    float evv = (j < 4) ? lo[j] : hi[j - 4];
                    float v = evv + bf2f((unsigned short)a8[j]) + bf2f((unsigned short)d8[j]);
                    o[j] = f2bf(fmaxf(v, 0.f));
                }
                *(u16x8*)(X0 + srow * 136 + q * 32 + i * 8) = *(u16x8*)o;
                *(u16x8*)(Hs + srow * 136 + q * 32 + i * 8) = h8;
            }
        }
        __syncthreads();
        f32x4 acc[4][2];
        zero_acc(acc);
        gemm64(X0, wf1, acc, lane);
        __syncthreads();
        epi_lds(X1, acc, b1_0, b1_1, c0, rbase);
        __syncthreads();
        zero_acc(acc);
        gemm64(X1, wf2, acc, lane);
        epi_lds(X0, acc, b2_0, b2_1, c0, rbase);
        __syncthreads();
        zero_acc(acc);
        gemm64(X0, wf3, acc, lane);
#pragma unroll
        for (int mt = 0; mt < 4; ++mt)
#pragma unroll
            for (int r = 0; r < 4; ++r) {
                int row = mt * 16 + rbase + r;
                int dofs = doff_lds[row];
                float h0 = bf2f(Hs[row * 136 + c0]);
                float h1 = bf2f(Hs[row * 136 + c0 + 16]);
                atomicAdd(agg + dofs + c0,      (acc[mt][0][r] + b3_0) * h0);
                atomicAdd(agg + dofs + c0 + 16, (acc[mt][1][r] + b3_1) * h1);
            }
    }
}

// ================= node output (fallback path: reads agg f32) =================
__global__ __launch_bounds__(256, 3)
void k_nodeout(const unsigned short* __restrict__ AH,
               const float* __restrict__ agg,
               const unsigned short* __restrict__ Wb,
               const float* __restrict__ bpd, const float* __restrict__ bpu,
               const float* __restrict__ bt1, const float* __restrict__ bt2,
               float* __restrict__ out) {
    __shared__ unsigned short Xh[64 * 136];
    __shared__ unsigned short Xa[64 * 136];
    int tid = threadIdx.x, lane = tid & 63, wv = tid >> 6;
    int n0 = blockIdx.x * 64;
    {
        int row = tid >> 2, q = tid & 3;
        int n = n0 + row;
        if (n < NN) {
            const u16x8* hp = (const u16x8*)(AH + (size_t)n * 256 + 128 + q * 32);
#pragma unroll
            for (int i = 0; i < 4; ++i)
                *(u16x8*)(Xh + row * 136 + q * 32 + i * 8) = hp[i];
            stage_f32row(Xa + row * 136 + q * 32,
                         (const f32x4*)(agg + (size_t)n * 128 + q * 32));
        } else {
            u16x8 z = {0, 0, 0, 0, 0, 0, 0, 0};
#pragma unroll
            for (int i = 0; i < 4; ++i) {
                *(u16x8*)(Xh + row * 136 + q * 32 + i * 8) = z;
                *(u16x8*)(Xa + row * 136 + q * 32 + i * 8) = z;
            }
        }
    }
    __syncthreads();
    bf16x8 wfa[4][2], wfb[4][2];
    load_wfrags(Wb + 5 * 16384, wv, lane, wfa);
    load_wfrags(Wb + 6 * 16384, wv, lane, wfb);
    int c0 = 32 * wv + (lane & 15);
    int rbase = (lane >> 4) * 4;
    f32x4 acc[4][2];
    zero_acc(acc);
    gemm64(Xh, wfa, acc, lane);
    gemm64(Xa, wfb, acc, lane);
    float bb0 = bpd[c0] + bpu[c0], bb1 = bpd[c0 + 16] + bpu[c0 + 16];
    __syncthreads();
    epi_lds(Xh, acc, bb0, bb1, c0, rbase);
    __syncthreads();
    load_wfrags(Wb + 7 * 16384, wv, lane, wfa);
    zero_acc(acc);
    gemm64(Xh, wfa, acc, lane);
    float b10 = bt1[c0], b11 = bt1[c0 + 16];
    __syncthreads();
    epi_lds(Xa, acc, b10, b11, c0, rbase);
    __syncthreads();
    load_wfrags(Wb + 8 * 16384, wv, lane, wfb);
    zero_acc(acc);
    gemm64(Xa, wfb, acc, lane);
    float b20 = bt2[c0], b21 = bt2[c0 + 16];
#pragma unroll
    for (int mt = 0; mt < 4; ++mt)
#pragma unroll
        for (int r = 0; r < 4; ++r) {
            int n = n0 + mt * 16 + rbase + r;
            if (n < NN) {
                out[(size_t)n * 128 + c0]      = acc[mt][0][r] + b20;
                out[(size_t)n * 128 + c0 + 16] = acc[mt][1][r] + b21;
            }
        }
}

extern "C" void kernel_launch(void* const* d_in, const int* in_sizes, int n_in,
                              void* d_out, int out_size, void* d_ws, size_t ws_size,
                              hipStream_t stream) {
    (void)in_sizes; (void)n_in; (void)out_size;
    const float* node_feat = (const float*)d_in[0];
    const float* edge_feat = (const float*)d_in[1];
    const int*   src  = (const int*)d_in[2];
    const int*   dst  = (const int*)d_in[3];
    const float* Wsrc = (const float*)d_in[4];  const float* bsrc = (const float*)d_in[5];
    const float* Wdst = (const float*)d_in[6];  const float* bdst = (const float*)d_in[7];
    const float* Wphi1 = (const float*)d_in[8]; const float* bphi1 = (const float*)d_in[9];
    const float* Wphi2 = (const float*)d_in[10];const float* bphi2 = (const float*)d_in[11];
    const float* Wphi3 = (const float*)d_in[12];const float* bphi3 = (const float*)d_in[13];
    const float* Wth1 = (const float*)d_in[14]; const float* bth1 = (const float*)d_in[15];
    const float* Wth2 = (const float*)d_in[16]; const float* bth2 = (const float*)d_in[17];
    const float* Wpd  = (const float*)d_in[18]; const float* bpd  = (const float*)d_in[19];
    const float* Wpu  = (const float*)d_in[20]; const float* bpu  = (const float*)d_in[21];

    // workspace carve (~272.6 MB primary)
    char* ws = (char*)d_ws;
    size_t off = 0;
    unsigned short* Wb   = (unsigned short*)(ws + off); off += 294912;
    unsigned short* AH   = (unsigned short*)(ws + off); off += 25600000;   // [Asrc|Hb]
    unsigned short* Adst = (unsigned short*)(ws + off); off += 12800000;
    float*          agg  = (float*)(ws + off);          off += 25600000;
    int*            cnt  = (int*)(ws + off);            off += 200064;
    int*            rowptr = (int*)(ws + off);          off += 200064;
    int*            bsum = (int*)(ws + off);            off += 1024;
    int*            pos  = (int*)(ws + off);            off += 3200000;
    unsigned short* Mbuf = (unsigned short*)(ws + off); off += 204800000;
    bool primary = (ws_size >= off);

    k_wconv<<<36, 256, 0, stream>>>(Wsrc, Wdst, Wphi1, Wphi2, Wphi3,
                                    Wpd, Wpu, Wth1, Wth2, Wb);
    k_nodepre<<<782, 256, 0, stream>>>(node_feat, Wb, bsrc, bdst, AH, Adst);

    if (primary) {
        hipMemsetAsync(cnt, 0, (size_t)NN * 4, stream);
        k_hist<<<3125, 256, 0, stream>>>(dst, cnt);
        k_scan1<<<NBLK_SCAN, 256, 0, stream>>>(cnt, bsum);
        k_scan2<<<1, 256, 0, stream>>>(bsum);
        k_scan3<<<NBLK_SCAN, 256, 0, stream>>>(cnt, bsum, rowptr);
        k_pos<<<3125, 256, 0, stream>>>(dst, cnt, pos);
        k_edgeB<<<GRID_E, 256, 0, stream>>>(edge_feat, src, dst, pos,
                                            AH, Adst, Wb,
                                            bphi1, bphi2, bphi3, Mbuf);
        k_nodeoutF<<<782, 256, 0, stream>>>(AH, Mbuf, rowptr, Wb,
                                            bpd, bpu, bth1, bth2, (float*)d_out);
    } else {
        hipMemsetAsync(agg, 0, (size_t)NN * 128 * 4, stream);
        k_edge_atomic<<<1024, 256, 0, stream>>>(edge_feat, src, dst,
                                                AH, Adst, Wb,
                                                bphi1, bphi2, bphi3, agg);
        k_nodeout<<<782, 256, 0, stream>>>(AH, agg, Wb, bpd, bpu, bth1, bth2,
                                           (float*)d_out);
    }
}

// Round 7
// 523.544 us; speedup vs baseline: 1.2707x; 1.2707x over previous
//
#include <hip/hip_runtime.h>
#include <hip/hip_bf16.h>

#define NN 50000
#define NE 800000
#define NT_E 12500      // 800000 / 64
#define GRID_E 768
#define NBLK_SCAN 196   // ceil(50000/256)

typedef __attribute__((ext_vector_type(8))) short bf16x8;
typedef __attribute__((ext_vector_type(4))) float f32x4;
typedef __attribute__((ext_vector_type(2))) float f32x2;
typedef __attribute__((ext_vector_type(8))) unsigned short u16x8;
typedef __attribute__((ext_vector_type(2))) unsigned short u16x2;

__device__ __forceinline__ unsigned short f2bf(float f) {
    union { float f; unsigned u; } v; v.f = f;
    unsigned r = v.u + 0x7FFFu + ((v.u >> 16) & 1u);   // RNE
    return (unsigned short)(r >> 16);
}
__device__ __forceinline__ float bf2f(unsigned short h) {
    union { unsigned u; float f; } v; v.u = ((unsigned)h) << 16;
    return v.f;
}
__device__ __forceinline__ f32x4 mfma16(bf16x8 a, bf16x8 b, f32x4 c) {
    return __builtin_amdgcn_mfma_f32_16x16x32_bf16(a, b, c, 0, 0, 0);
}
// barrier WITHOUT vmcnt drain: cross-thread comm is via LDS only, so
// lgkmcnt(0)+s_barrier suffices; global loads/stores stay in flight.
__device__ __forceinline__ void syncl() {
    asm volatile("s_waitcnt lgkmcnt(0)\n\ts_barrier" ::: "memory");
}

__device__ __forceinline__ void load_wfrags(const unsigned short* __restrict__ Wb,
                                            int wv, int lane, bf16x8 (&wf)[4][2]) {
#pragma unroll
    for (int kk = 0; kk < 4; ++kk)
#pragma unroll
        for (int j = 0; j < 2; ++j) {
            int row = 32 * wv + 16 * j + (lane & 15);
            int col = 32 * kk + 8 * (lane >> 4);
            wf[kk][j] = *(const bf16x8*)(Wb + row * 128 + col);
        }
}

__device__ __forceinline__ void zero_acc(f32x4 (&acc)[4][2]) {
#pragma unroll
    for (int mt = 0; mt < 4; ++mt)
#pragma unroll
        for (int j = 0; j < 2; ++j) {
            f32x4 z = {0.f, 0.f, 0.f, 0.f};
            acc[mt][j] = z;
        }
}

__device__ __forceinline__ void gemm64(const unsigned short* __restrict__ X,
                                       const bf16x8 (&wf)[4][2], f32x4 (&acc)[4][2], int lane) {
#pragma unroll
    for (int kk = 0; kk < 4; ++kk) {
        bf16x8 a[4];
#pragma unroll
        for (int mt = 0; mt < 4; ++mt) {
            int row = mt * 16 + (lane & 15);
            a[mt] = *(const bf16x8*)(X + row * 136 + kk * 32 + 8 * (lane >> 4));
        }
#pragma unroll
        for (int mt = 0; mt < 4; ++mt) {
            acc[mt][0] = mfma16(a[mt], wf[kk][0], acc[mt][0]);
            acc[mt][1] = mfma16(a[mt], wf[kk][1], acc[mt][1]);
        }
    }
}

__device__ __forceinline__ void epi_lds(unsigned short* __restrict__ Xo,
                                        const f32x4 (&acc)[4][2],
                                        float bb0, float bb1, int c0, int rbase) {
#pragma unroll
    for (int mt = 0; mt < 4; ++mt)
#pragma unroll
        for (int r = 0; r < 4; ++r) {
            int row = mt * 16 + rbase + r;
            Xo[row * 136 + c0]      = f2bf(fmaxf(acc[mt][0][r] + bb0, 0.f));
            Xo[row * 136 + c0 + 16] = f2bf(fmaxf(acc[mt][1][r] + bb1, 0.f));
        }
}

// epilogue WITHOUT relu: e_emb + b3 -> bf16 LDS tile
__device__ __forceinline__ void epi_lds_norelu(unsigned short* __restrict__ Xo,
                                               const f32x4 (&acc)[4][2],
                                               float bb0, float bb1, int c0, int rbase) {
#pragma unroll
    for (int mt = 0; mt < 4; ++mt)
#pragma unroll
        for (int r = 0; r < 4; ++r) {
            int row = mt * 16 + rbase + r;
            Xo[row * 136 + c0]      = f2bf(acc[mt][0][r] + bb0);
            Xo[row * 136 + c0 + 16] = f2bf(acc[mt][1][r] + bb1);
        }
}

__device__ __forceinline__ void stage_f32row(unsigned short* __restrict__ Xrow,
                                             const f32x4* __restrict__ p) {
#pragma unroll
    for (int i = 0; i < 4; ++i) {
        f32x4 lo = p[2 * i], hi = p[2 * i + 1];
        unsigned short tmp[8];
#pragma unroll
        for (int j = 0; j < 4; ++j) { tmp[j] = f2bf(lo[j]); tmp[4 + j] = f2bf(hi[j]); }
        *(u16x8*)(Xrow + i * 8) = *(u16x8*)tmp;
    }
}

// ================= convert 9 DxD fp32 weights to bf16 =================
__global__ void k_wconv(const float* w0, const float* w1, const float* w2,
                        const float* w3, const float* w4, const float* w5,
                        const float* w6, const float* w7, const float* w8,
                        unsigned short* out) {
    const float* ws[9] = {w0, w1, w2, w3, w4, w5, w6, w7, w8};
    int m = blockIdx.x >> 2;
    int part = blockIdx.x & 3;
    const float* w = ws[m] + part * 4096 + threadIdx.x * 16;
    unsigned short* o = out + m * 16384 + part * 4096 + threadIdx.x * 16;
    float f[16];
#pragma unroll
    for (int i = 0; i < 4; ++i) *(f32x4*)(f + 4 * i) = ((const f32x4*)w)[i];
    unsigned short tmp[16];
#pragma unroll
    for (int i = 0; i < 16; ++i) tmp[i] = f2bf(f[i]);
    ((u16x8*)o)[0] = *(u16x8*)tmp;
    ((u16x8*)o)[1] = *(u16x8*)(tmp + 8);
}

// ================= sort: hist -> 3-kernel scan -> position =================
__global__ void k_hist(const int* __restrict__ dst, int* __restrict__ cnt) {
    int i = blockIdx.x * 256 + threadIdx.x;
    if (i < NE) atomicAdd(&cnt[dst[i]], 1);
}

__global__ void k_scan1(const int* __restrict__ c, int* __restrict__ bsum) {
    __shared__ int red[256];
    int i = blockIdx.x * 256 + threadIdx.x;
    red[threadIdx.x] = (i < NN) ? c[i] : 0;
    __syncthreads();
    for (int off = 128; off > 0; off >>= 1) {
        if (threadIdx.x < off) red[threadIdx.x] += red[threadIdx.x + off];
        __syncthreads();
    }
    if (threadIdx.x == 0) bsum[blockIdx.x] = red[0];
}

__global__ void k_scan2(int* __restrict__ bsum) {   // 1 block, 256 threads
    __shared__ int s[256];
    int t = threadIdx.x;
    s[t] = (t < NBLK_SCAN) ? bsum[t] : 0;
    __syncthreads();
    for (int off = 1; off < 256; off <<= 1) {
        int v = (t >= off) ? s[t - off] : 0;
        __syncthreads();
        s[t] += v;
        __syncthreads();
    }
    if (t < NBLK_SCAN) bsum[t] = (t == 0) ? 0 : s[t - 1];
}

__global__ void k_scan3(int* __restrict__ cnt, const int* __restrict__ bsum,
                        int* __restrict__ rowptr) {
    __shared__ int s[256];
    int t = threadIdx.x;
    int i = blockIdx.x * 256 + t;
    int v = (i < NN) ? cnt[i] : 0;
    s[t] = v;
    __syncthreads();
    for (int off = 1; off < 256; off <<= 1) {
        int x = (t >= off) ? s[t - off] : 0;
        __syncthreads();
        s[t] += x;
        __syncthreads();
    }
    int excl = bsum[blockIdx.x] + s[t] - v;
    if (i < NN) { rowptr[i] = excl; cnt[i] = excl; }   // cnt becomes cursor
    if (i == 0) rowptr[NN] = NE;
}

__global__ void k_pos(const int* __restrict__ dst, int* __restrict__ cursor,
                      int* __restrict__ pos) {
    int i = blockIdx.x * 256 + threadIdx.x;
    if (i < NE) pos[i] = atomicAdd(&cursor[dst[i]], 1);
}

// ================= node pre: AH = [Asrc row | Hb row], Adst =================
__global__ __launch_bounds__(256, 3)
void k_nodepre(const float* __restrict__ h,
               const unsigned short* __restrict__ Wb,
               const float* __restrict__ bsrc, const float* __restrict__ bdst,
               unsigned short* __restrict__ AH, unsigned short* __restrict__ Adst) {
    __shared__ unsigned short X[64 * 136];
    int tid = threadIdx.x, lane = tid & 63, wv = tid >> 6;
    int n0 = blockIdx.x * 64;
    {
        int row = tid >> 2, q = tid & 3;
        int n = n0 + row;
        if (n < NN) {
            unsigned short tmp[32];
            const f32x4* hp = (const f32x4*)(h + (size_t)n * 128 + q * 32);
#pragma unroll
            for (int i = 0; i < 8; ++i) {
                f32x4 v = hp[i];
#pragma unroll
                for (int j = 0; j < 4; ++j) tmp[i * 4 + j] = f2bf(v[j]);
            }
#pragma unroll
            for (int i = 0; i < 4; ++i)
                *(u16x8*)(X + row * 136 + q * 32 + i * 8) = *(u16x8*)(tmp + i * 8);
            u16x8* hb = (u16x8*)(AH + (size_t)n * 256 + 128 + q * 32);
#pragma unroll
            for (int i = 0; i < 4; ++i) hb[i] = *(u16x8*)(tmp + i * 8);
        } else {
            u16x8 z = {0, 0, 0, 0, 0, 0, 0, 0};
#pragma unroll
            for (int i = 0; i < 4; ++i) *(u16x8*)(X + row * 136 + q * 32 + i * 8) = z;
        }
    }
    __syncthreads();

    bf16x8 wfS[4][2], wfD[4][2];
    load_wfrags(Wb, wv, lane, wfS);
    load_wfrags(Wb + 16384, wv, lane, wfD);
    f32x4 accS[4][2], accD[4][2];
    zero_acc(accS); zero_acc(accD);
    gemm64(X, wfS, accS, lane);
    gemm64(X, wfD, accD, lane);

    int c0 = 32 * wv + (lane & 15);
    float bs0 = bsrc[c0], bs1 = bsrc[c0 + 16];
    float bd0 = bdst[c0], bd1 = bdst[c0 + 16];
    int rbase = (lane >> 4) * 4;
#pragma unroll
    for (int mt = 0; mt < 4; ++mt)
#pragma unroll
        for (int r = 0; r < 4; ++r) {
            int n = n0 + mt * 16 + rbase + r;
            if (n < NN) {
                AH[(size_t)n * 256 + c0]        = f2bf(accS[mt][0][r] + bs0);
                AH[(size_t)n * 256 + c0 + 16]   = f2bf(accS[mt][1][r] + bs1);
                Adst[(size_t)n * 128 + c0]      = f2bf(accD[mt][0][r] + bd0);
                Adst[(size_t)n * 128 + c0 + 16] = f2bf(accD[mt][1][r] + bd1);
            }
        }
}

// ===== edge MLP: 3 W-sets resident (cap 170 @ 3blk/CU), h-in-regs, idx prefetch
__global__ __launch_bounds__(256, 3)
void k_edgeB(const float* __restrict__ ef,
             const int* __restrict__ src, const int* __restrict__ dst,
             const int* __restrict__ pos,
             const unsigned short* __restrict__ AH,
             const unsigned short* __restrict__ Adst,
             const unsigned short* __restrict__ Wb,
             const float* __restrict__ b1, const float* __restrict__ b2,
             const float* __restrict__ b3,
             unsigned short* __restrict__ Mbuf) {
    __shared__ __align__(16) char sh[35072];
    unsigned short* X0 = (unsigned short*)sh;             // [64][136]
    unsigned short* X1 = (unsigned short*)(sh + 17408);   // [64][136]
    int*         posarr = (int*)(sh + 34816);             // [64]

    int tid = threadIdx.x, lane = tid & 63, wv = tid >> 6;

    // ALL THREE weight sets resident: 96 VGPR + ~60 base = ~156 < 170 cap.
    // (R4 A/B: residency >> per-tile reload; R6 proved this needs the 3-blk cap.)
    bf16x8 wf1[4][2], wf2[4][2], wf3[4][2];
    load_wfrags(Wb + 2 * 16384, wv, lane, wf1);   // Wphi1
    load_wfrags(Wb + 3 * 16384, wv, lane, wf2);   // Wphi2
    load_wfrags(Wb + 4 * 16384, wv, lane, wf3);   // Wphi3

    int c0 = 32 * wv + (lane & 15);
    float b1_0 = b1[c0], b1_1 = b1[c0 + 16];
    float b2_0 = b2[c0], b2_1 = b2[c0 + 16];
    float b3_0 = b3[c0], b3_1 = b3[c0 + 16];
    int rbase = (lane >> 4) * 4;
    int srow = tid >> 2, q = tid & 3;

    // contiguous chunk per block: ef stream stays sequential per block
    int b = blockIdx.x, nb = gridDim.x;
    int qt = NT_E / nb, rt = NT_E % nb;
    int t0 = (b < rt) ? b * (qt + 1) : rt * (qt + 1) + (b - rt) * qt;
    int t1 = t0 + ((b < rt) ? qt + 1 : qt);

    // idx prefetch: (src,dst,pos) for tile t loaded during tile t-1's GEMMs
    int sN, dN, pN;
    {
        int e = t0 * 64 + srow;
        sN = src[e]; dN = dst[e]; pN = pos[e];
    }

    for (int t = t0; t < t1; ++t) {
        int s = sN, d = dN, p = pN;
        u16x8 hbr[4];                          // h_src slice, stays in regs
        syncl();                               // prev store-phase LDS reads done
        {   // stage: X0 = relu(ef + AH.a[src] + Adst[dst]); hbr = AH.h[src]
            int e = t * 64 + srow;
            if (q == 0) posarr[srow] = p;
            const f32x4* ep = (const f32x4*)(ef + (size_t)e * 128 + q * 32);
            const u16x8* ap = (const u16x8*)(AH + (size_t)s * 256 + q * 32);
            const u16x8* hp = (const u16x8*)(AH + (size_t)s * 256 + 128 + q * 32);
            const u16x8* dp = (const u16x8*)(Adst + (size_t)d * 128 + q * 32);
#pragma unroll
            for (int i = 0; i < 4; ++i) {
                u16x8 a8 = ap[i], d8 = dp[i];
                hbr[i] = hp[i];
                f32x4 lo = ep[2 * i], hi = ep[2 * i + 1];
                unsigned short o[8];
#pragma unroll
                for (int j = 0; j < 8; ++j) {
                    float evv = (j < 4) ? lo[j] : hi[j - 4];
                    float v = evv + bf2f((unsigned short)a8[j]) + bf2f((unsigned short)d8[j]);
                    o[j] = f2bf(fmaxf(v, 0.f));
                }
                *(u16x8*)(X0 + srow * 136 + q * 32 + i * 8) = *(u16x8*)o;
            }
        }
        if (t + 1 < t1) {                      // issue next idx loads; latency
            int e = (t + 1) * 64 + srow;       // hides under the GEMM phases
            sN = src[e]; dN = dst[e]; pN = pos[e];
        }
        syncl();                               // X0/posarr visible
        f32x4 acc[4][2];
        zero_acc(acc);
        gemm64(X0, wf1, acc, lane);
        syncl();                               // X0 reads done
        epi_lds(X1, acc, b1_0, b1_1, c0, rbase);
        syncl();                               // X1 ready
        zero_acc(acc);
        gemm64(X1, wf2, acc, lane);
        epi_lds(X0, acc, b2_0, b2_1, c0, rbase);
        syncl();                               // X0 ready (X1 reads also done)
        zero_acc(acc);
        gemm64(X0, wf3, acc, lane);
        syncl();                               // X1 free (gemm2 reads long done)
        epi_lds_norelu(X1, acc, b3_0, b3_1, c0, rbase);  // X1 = e_emb + b3 (bf16)
        syncl();                               // X1 ready
        // m = h_src * e_emb in staging layout; 64B store per thread to Mbuf
        {
            int posr = posarr[srow];
            unsigned short* mp = Mbuf + (size_t)posr * 128 + q * 32;
#pragma unroll
            for (int i = 0; i < 4; ++i) {
                u16x8 ev = *(const u16x8*)(X1 + srow * 136 + q * 32 + i * 8);
                u16x8 o;
#pragma unroll
                for (int j = 0; j < 8; ++j)
                    o[j] = f2bf(bf2f((unsigned short)ev[j]) * bf2f((unsigned short)hbr[i][j]));
                *(u16x8*)(mp + i * 8) = o;
            }
        }
    }
}

// ===== fused aggregate + node output (primary path) =====
__global__ __launch_bounds__(256, 3)
void k_nodeoutF(const unsigned short* __restrict__ AH,
                const unsigned short* __restrict__ Mbuf,
                const int* __restrict__ rowptr,
                const unsigned short* __restrict__ Wb,
                const float* __restrict__ bpd, const float* __restrict__ bpu,
                const float* __restrict__ bt1, const float* __restrict__ bt2,
                float* __restrict__ out) {
    __shared__ unsigned short Xh[64 * 136];
    __shared__ unsigned short Xa[64 * 136];
    int tid = threadIdx.x, lane = tid & 63, wv = tid >> 6;
    int n0 = blockIdx.x * 64;
    {   // stage Xh = AH.h
        int row = tid >> 2, q = tid & 3;
        int n = n0 + row;
        if (n < NN) {
            const u16x8* hp = (const u16x8*)(AH + (size_t)n * 256 + 128 + q * 32);
#pragma unroll
            for (int i = 0; i < 4; ++i)
                *(u16x8*)(Xh + row * 136 + q * 32 + i * 8) = hp[i];
        } else {
            u16x8 z = {0, 0, 0, 0, 0, 0, 0, 0};
#pragma unroll
            for (int i = 0; i < 4; ++i)
                *(u16x8*)(Xh + row * 136 + q * 32 + i * 8) = z;
        }
    }
    {   // fused agg: one node per wave-iteration, sequential Mbuf rows
#pragma unroll 1
        for (int it = 0; it < 16; ++it) {
            int row = wv * 16 + it;
            int n = n0 + row;
            float a0 = 0.f, a1 = 0.f;
            if (n < NN) {
                int j0 = rowptr[n], j1 = rowptr[n + 1];
                int j = j0;
                for (; j + 3 < j1; j += 4) {
                    u16x2 v0 = *(const u16x2*)(Mbuf + (size_t)j * 128 + lane * 2);
                    u16x2 v1 = *(const u16x2*)(Mbuf + (size_t)(j + 1) * 128 + lane * 2);
                    u16x2 v2 = *(const u16x2*)(Mbuf + (size_t)(j + 2) * 128 + lane * 2);
                    u16x2 v3 = *(const u16x2*)(Mbuf + (size_t)(j + 3) * 128 + lane * 2);
                    a0 += bf2f(v0[0]) + bf2f(v1[0]) + bf2f(v2[0]) + bf2f(v3[0]);
                    a1 += bf2f(v0[1]) + bf2f(v1[1]) + bf2f(v2[1]) + bf2f(v3[1]);
                }
                for (; j < j1; ++j) {
                    u16x2 v = *(const u16x2*)(Mbuf + (size_t)j * 128 + lane * 2);
                    a0 += bf2f(v[0]); a1 += bf2f(v[1]);
                }
            }
            Xa[row * 136 + lane * 2]     = f2bf(a0);
            Xa[row * 136 + lane * 2 + 1] = f2bf(a1);
        }
    }
    __syncthreads();
    bf16x8 wfa[4][2], wfb[4][2];
    load_wfrags(Wb + 5 * 16384, wv, lane, wfa);   // Wpd
    load_wfrags(Wb + 6 * 16384, wv, lane, wfb);   // Wpu
    int c0 = 32 * wv + (lane & 15);
    int rbase = (lane >> 4) * 4;
    f32x4 acc[4][2];
    zero_acc(acc);
    gemm64(Xh, wfa, acc, lane);
    gemm64(Xa, wfb, acc, lane);
    float bb0 = bpd[c0] + bpu[c0], bb1 = bpd[c0 + 16] + bpu[c0 + 16];
    __syncthreads();
    epi_lds(Xh, acc, bb0, bb1, c0, rbase);
    __syncthreads();
    load_wfrags(Wb + 7 * 16384, wv, lane, wfa);   // Wth1
    zero_acc(acc);
    gemm64(Xh, wfa, acc, lane);
    float b10 = bt1[c0], b11 = bt1[c0 + 16];
    __syncthreads();
    epi_lds(Xa, acc, b10, b11, c0, rbase);
    __syncthreads();
    load_wfrags(Wb + 8 * 16384, wv, lane, wfb);   // Wth2
    zero_acc(acc);
    gemm64(Xa, wfb, acc, lane);
    float b20 = bt2[c0], b21 = bt2[c0 + 16];
#pragma unroll
    for (int mt = 0; mt < 4; ++mt)
#pragma unroll
        for (int r = 0; r < 4; ++r) {
            int n = n0 + mt * 16 + rbase + r;
            if (n < NN) {
                out[(size_t)n * 128 + c0]      = acc[mt][0][r] + b20;
                out[(size_t)n * 128 + c0 + 16] = acc[mt][1][r] + b21;
            }
        }
}

// ============ fallback edge kernel (direct atomics, small-ws path) ============
__global__ __launch_bounds__(256, 2)
void k_edge_atomic(const float* __restrict__ ef,
                   const int* __restrict__ src, const int* __restrict__ dst,
                   const unsigned short* __restrict__ AH,
                   const unsigned short* __restrict__ Adst,
                   const unsigned short* __restrict__ Wb,
                   const float* __restrict__ b1, const float* __restrict__ b2,
                   const float* __restrict__ b3,
                   float* __restrict__ agg) {
    __shared__ unsigned short X0[64 * 136];
    __shared__ unsigned short X1[64 * 136];
    __shared__ unsigned short Hs[64 * 136];
    __shared__ int doff_lds[64];

    int tid = threadIdx.x, lane = tid & 63, wv = tid >> 6;
    bf16x8 wf1[4][2], wf2[4][2], wf3[4][2];
    load_wfrags(Wb + 2 * 16384, wv, lane, wf1);
    load_wfrags(Wb + 3 * 16384, wv, lane, wf2);
    load_wfrags(Wb + 4 * 16384, wv, lane, wf3);

    int c0 = 32 * wv + (lane & 15);
    float b1_0 = b1[c0], b1_1 = b1[c0 + 16];
    float b2_0 = b2[c0], b2_1 = b2[c0 + 16];
    float b3_0 = b3[c0], b3_1 = b3[c0 + 16];
    int rbase = (lane >> 4) * 4;
    int srow = tid >> 2, q = tid & 3;

    for (int t = blockIdx.x; t < NT_E; t += gridDim.x) {
        int e0 = t * 64;
        __syncthreads();
        {
            int e = e0 + srow;
            int s = src[e], d = dst[e];
            if (q == 0) doff_lds[srow] = d * 128;
            const f32x4* ep = (const f32x4*)(ef + (size_t)e * 128 + q * 32);
            const u16x8* ap = (const u16x8*)(AH + (size_t)s * 256 + q * 32);
            const u16x8* hp = (const u16x8*)(AH + (size_t)s * 256 + 128 + q * 32);
            const u16x8* dp = (const u16x8*)(Adst + (size_t)d * 128 + q * 32);
#pragma unroll
            for (int i = 0; i < 4; ++i) {
                u16x8 a8 = ap[i], d8 = dp[i], h8 = hp[i];
                f32x4 lo = ep[2 * i], hi = ep[2 * i + 1];
                unsigned short o[8];
#pragma unroll
                for (int j = 0; j < 8; ++j) {
                    float evv = (j < 4) ? lo[j] : hi[j - 4];
                    float v = evv + bf2f((unsigned short)a8[j]) + bf2f((unsigned short)d8[j]);
                    o[j] = f2bf(fmaxf(v, 0.f));
                }
                *(u16x8*)(X0 + srow * 136 + q * 32 + i * 8) = *(u16x8*)o;
                *(u16x8*)(Hs + srow * 136 + q * 32 + i * 8) = h8;
            }
        }
        __syncthreads();
        f32x4 acc[4][2];
        zero_acc(acc);
        gemm64(X0, wf1, acc, lane);
        __syncthreads();
        epi_lds(X1, acc, b1_0, b1_1, c0, rbase);
        __syncthreads();
        zero_acc(acc);
        gemm64(X1, wf2, acc, lane);
        epi_lds(X0, acc, b2_0, b2_1, c0, rbase);
        __syncthreads();
        zero_acc(acc);
        gemm64(X0, wf3, acc, lane);
#pragma unroll
        for (int mt = 0; mt < 4; ++mt)
#pragma unroll
            for (int r = 0; r < 4; ++r) {
                int row = mt * 16 + rbase + r;
                int dofs = doff_lds[row];
                float h0 = bf2f(Hs[row * 136 + c0]);
                float h1 = bf2f(Hs[row * 136 + c0 + 16]);
                atomicAdd(agg + dofs + c0,      (acc[mt][0][r] + b3_0) * h0);
                atomicAdd(agg + dofs + c0 + 16, (acc[mt][1][r] + b3_1) * h1);
            }
    }
}

// ================= node output (fallback path: reads agg f32) =================
__global__ __launch_bounds__(256, 3)
void k_nodeout(const unsigned short* __restrict__ AH,
               const float* __restrict__ agg,
               const unsigned short* __restrict__ Wb,
               const float* __restrict__ bpd, const float* __restrict__ bpu,
               const float* __restrict__ bt1, const float* __restrict__ bt2,
               float* __restrict__ out) {
    __shared__ unsigned short Xh[64 * 136];
    __shared__ unsigned short Xa[64 * 136];
    int tid = threadIdx.x, lane = tid & 63, wv = tid >> 6;
    int n0 = blockIdx.x * 64;
    {
        int row = tid >> 2, q = tid & 3;
        int n = n0 + row;
        if (n < NN) {
            const u16x8* hp = (const u16x8*)(AH + (size_t)n * 256 + 128 + q * 32);
#pragma unroll
            for (int i = 0; i < 4; ++i)
                *(u16x8*)(Xh + row * 136 + q * 32 + i * 8) = hp[i];
            stage_f32row(Xa + row * 136 + q * 32,
                         (const f32x4*)(agg + (size_t)n * 128 + q * 32));
        } else {
            u16x8 z = {0, 0, 0, 0, 0, 0, 0, 0};
#pragma unroll
            for (int i = 0; i < 4; ++i) {
                *(u16x8*)(Xh + row * 136 + q * 32 + i * 8) = z;
                *(u16x8*)(Xa + row * 136 + q * 32 + i * 8) = z;
            }
        }
    }
    __syncthreads();
    bf16x8 wfa[4][2], wfb[4][2];
    load_wfrags(Wb + 5 * 16384, wv, lane, wfa);
    load_wfrags(Wb + 6 * 16384, wv, lane, wfb);
    int c0 = 32 * wv + (lane & 15);
    int rbase = (lane >> 4) * 4;
    f32x4 acc[4][2];
    zero_acc(acc);
    gemm64(Xh, wfa, acc, lane);
    gemm64(Xa, wfb, acc, lane);
    float bb0 = bpd[c0] + bpu[c0], bb1 = bpd[c0 + 16] + bpu[c0 + 16];
    __syncthreads();
    epi_lds(Xh, acc, bb0, bb1, c0, rbase);
    __syncthreads();
    load_wfrags(Wb + 7 * 16384, wv, lane, wfa);
    zero_acc(acc);
    gemm64(Xh, wfa, acc, lane);
    float b10 = bt1[c0], b11 = bt1[c0 + 16];
    __syncthreads();
    epi_lds(Xa, acc, b10, b11, c0, rbase);
    __syncthreads();
    load_wfrags(Wb + 8 * 16384, wv, lane, wfb);
    zero_acc(acc);
    gemm64(Xa, wfb, acc, lane);
    float b20 = bt2[c0], b21 = bt2[c0 + 16];
#pragma unroll
    for (int mt = 0; mt < 4; ++mt)
#pragma unroll
        for (int r = 0; r < 4; ++r) {
            int n = n0 + mt * 16 + rbase + r;
            if (n < NN) {
                out[(size_t)n * 128 + c0]      = acc[mt][0][r] + b20;
                out[(size_t)n * 128 + c0 + 16] = acc[mt][1][r] + b21;
            }
        }
}

extern "C" void kernel_launch(void* const* d_in, const int* in_sizes, int n_in,
                              void* d_out, int out_size, void* d_ws, size_t ws_size,
                              hipStream_t stream) {
    (void)in_sizes; (void)n_in; (void)out_size;
    const float* node_feat = (const float*)d_in[0];
    const float* edge_feat = (const float*)d_in[1];
    const int*   src  = (const int*)d_in[2];
    const int*   dst  = (const int*)d_in[3];
    const float* Wsrc = (const float*)d_in[4];  const float* bsrc = (const float*)d_in[5];
    const float* Wdst = (const float*)d_in[6];  const float* bdst = (const float*)d_in[7];
    const float* Wphi1 = (const float*)d_in[8]; const float* bphi1 = (const float*)d_in[9];
    const float* Wphi2 = (const float*)d_in[10];const float* bphi2 = (const float*)d_in[11];
    const float* Wphi3 = (const float*)d_in[12];const float* bphi3 = (const float*)d_in[13];
    const float* Wth1 = (const float*)d_in[14]; const float* bth1 = (const float*)d_in[15];
    const float* Wth2 = (const float*)d_in[16]; const float* bth2 = (const float*)d_in[17];
    const float* Wpd  = (const float*)d_in[18]; const float* bpd  = (const float*)d_in[19];
    const float* Wpu  = (const float*)d_in[20]; const float* bpu  = (const float*)d_in[21];

    // workspace carve (~272.6 MB primary)
    char* ws = (char*)d_ws;
    size_t off = 0;
    unsigned short* Wb   = (unsigned short*)(ws + off); off += 294912;
    unsigned short* AH   = (unsigned short*)(ws + off); off += 25600000;   // [Asrc|Hb]
    unsigned short* Adst = (unsigned short*)(ws + off); off += 12800000;
    float*          agg  = (float*)(ws + off);          off += 25600000;
    int*            cnt  = (int*)(ws + off);            off += 200064;
    int*            rowptr = (int*)(ws + off);          off += 200064;
    int*            bsum = (int*)(ws + off);            off += 1024;
    int*            pos  = (int*)(ws + off);            off += 3200000;
    unsigned short* Mbuf = (unsigned short*)(ws + off); off += 204800000;
    bool primary = (ws_size >= off);

    k_wconv<<<36, 256, 0, stream>>>(Wsrc, Wdst, Wphi1, Wphi2, Wphi3,
                                    Wpd, Wpu, Wth1, Wth2, Wb);
    k_nodepre<<<782, 256, 0, stream>>>(node_feat, Wb, bsrc, bdst, AH, Adst);

    if (primary) {
        hipMemsetAsync(cnt, 0, (size_t)NN * 4, stream);
        k_hist<<<3125, 256, 0, stream>>>(dst, cnt);
        k_scan1<<<NBLK_SCAN, 256, 0, stream>>>(cnt, bsum);
        k_scan2<<<1, 256, 0, stream>>>(bsum);
        k_scan3<<<NBLK_SCAN, 256, 0, stream>>>(cnt, bsum, rowptr);
        k_pos<<<3125, 256, 0, stream>>>(dst, cnt, pos);
        k_edgeB<<<GRID_E, 256, 0, stream>>>(edge_feat, src, dst, pos,
                                            AH, Adst, Wb,
                                            bphi1, bphi2, bphi3, Mbuf);
        k_nodeoutF<<<782, 256, 0, stream>>>(AH, Mbuf, rowptr, Wb,
                                            bpd, bpu, bth1, bth2, (float*)d_out);
    } else {
        hipMemsetAsync(agg, 0, (size_t)NN * 128 * 4, stream);
        k_edge_atomic<<<1024, 256, 0, stream>>>(edge_feat, src, dst,
                                                AH, Adst, Wb,
                                                bphi1, bphi2, bphi3, agg);
        k_nodeout<<<782, 256, 0, stream>>>(AH, agg, Wb, bpd, bpu, bth1, bth2,
                                           (float*)d_out);
    }
}

// Round 8
// 511.326 us; speedup vs baseline: 1.3011x; 1.0239x over previous
//
#include <hip/hip_runtime.h>
#include <hip/hip_bf16.h>

#define NN 50000
#define NE 800000
#define NT_E 12500      // 800000 / 64
#define GRID_E 768
#define NBLK_SCAN 196   // ceil(50000/256)

typedef __attribute__((ext_vector_type(8))) short bf16x8;
typedef __attribute__((ext_vector_type(4))) float f32x4;
typedef __attribute__((ext_vector_type(2))) float f32x2;
typedef __attribute__((ext_vector_type(8))) unsigned short u16x8;
typedef __attribute__((ext_vector_type(2))) unsigned short u16x2;

__device__ __forceinline__ unsigned short f2bf(float f) {
    union { float f; unsigned u; } v; v.f = f;
    unsigned r = v.u + 0x7FFFu + ((v.u >> 16) & 1u);   // RNE
    return (unsigned short)(r >> 16);
}
__device__ __forceinline__ float bf2f(unsigned short h) {
    union { unsigned u; float f; } v; v.u = ((unsigned)h) << 16;
    return v.f;
}
__device__ __forceinline__ f32x4 mfma16(bf16x8 a, bf16x8 b, f32x4 c) {
    return __builtin_amdgcn_mfma_f32_16x16x32_bf16(a, b, c, 0, 0, 0);
}
// barrier WITHOUT vmcnt drain: cross-thread comm is via LDS only, so
// lgkmcnt(0)+s_barrier suffices; global loads/stores stay in flight.
__device__ __forceinline__ void syncl() {
    asm volatile("s_waitcnt lgkmcnt(0)\n\ts_barrier" ::: "memory");
}

__device__ __forceinline__ void load_wfrags(const unsigned short* __restrict__ Wb,
                                            int wv, int lane, bf16x8 (&wf)[4][2]) {
#pragma unroll
    for (int kk = 0; kk < 4; ++kk)
#pragma unroll
        for (int j = 0; j < 2; ++j) {
            int row = 32 * wv + 16 * j + (lane & 15);
            int col = 32 * kk + 8 * (lane >> 4);
            wf[kk][j] = *(const bf16x8*)(Wb + row * 128 + col);
        }
}

__device__ __forceinline__ void zero_acc(f32x4 (&acc)[4][2]) {
#pragma unroll
    for (int mt = 0; mt < 4; ++mt)
#pragma unroll
        for (int j = 0; j < 2; ++j) {
            f32x4 z = {0.f, 0.f, 0.f, 0.f};
            acc[mt][j] = z;
        }
}

__device__ __forceinline__ void gemm64(const unsigned short* __restrict__ X,
                                       const bf16x8 (&wf)[4][2], f32x4 (&acc)[4][2], int lane) {
#pragma unroll
    for (int kk = 0; kk < 4; ++kk) {
        bf16x8 a[4];
#pragma unroll
        for (int mt = 0; mt < 4; ++mt) {
            int row = mt * 16 + (lane & 15);
            a[mt] = *(const bf16x8*)(X + row * 136 + kk * 32 + 8 * (lane >> 4));
        }
#pragma unroll
        for (int mt = 0; mt < 4; ++mt) {
            acc[mt][0] = mfma16(a[mt], wf[kk][0], acc[mt][0]);
            acc[mt][1] = mfma16(a[mt], wf[kk][1], acc[mt][1]);
        }
    }
}

__device__ __forceinline__ void epi_lds(unsigned short* __restrict__ Xo,
                                        const f32x4 (&acc)[4][2],
                                        float bb0, float bb1, int c0, int rbase) {
#pragma unroll
    for (int mt = 0; mt < 4; ++mt)
#pragma unroll
        for (int r = 0; r < 4; ++r) {
            int row = mt * 16 + rbase + r;
            Xo[row * 136 + c0]      = f2bf(fmaxf(acc[mt][0][r] + bb0, 0.f));
            Xo[row * 136 + c0 + 16] = f2bf(fmaxf(acc[mt][1][r] + bb1, 0.f));
        }
}

// epilogue WITHOUT relu: e_emb + b3 -> bf16 LDS tile
__device__ __forceinline__ void epi_lds_norelu(unsigned short* __restrict__ Xo,
                                               const f32x4 (&acc)[4][2],
                                               float bb0, float bb1, int c0, int rbase) {
#pragma unroll
    for (int mt = 0; mt < 4; ++mt)
#pragma unroll
        for (int r = 0; r < 4; ++r) {
            int row = mt * 16 + rbase + r;
            Xo[row * 136 + c0]      = f2bf(acc[mt][0][r] + bb0);
            Xo[row * 136 + c0 + 16] = f2bf(acc[mt][1][r] + bb1);
        }
}

__device__ __forceinline__ void stage_f32row(unsigned short* __restrict__ Xrow,
                                             const f32x4* __restrict__ p) {
#pragma unroll
    for (int i = 0; i < 4; ++i) {
        f32x4 lo = p[2 * i], hi = p[2 * i + 1];
        unsigned short tmp[8];
#pragma unroll
        for (int j = 0; j < 4; ++j) { tmp[j] = f2bf(lo[j]); tmp[4 + j] = f2bf(hi[j]); }
        *(u16x8*)(Xrow + i * 8) = *(u16x8*)tmp;
    }
}

// ================= convert 9 DxD fp32 weights to bf16 =================
__global__ void k_wconv(const float* w0, const float* w1, const float* w2,
                        const float* w3, const float* w4, const float* w5,
                        const float* w6, const float* w7, const float* w8,
                        unsigned short* out) {
    const float* ws[9] = {w0, w1, w2, w3, w4, w5, w6, w7, w8};
    int m = blockIdx.x >> 2;
    int part = blockIdx.x & 3;
    const float* w = ws[m] + part * 4096 + threadIdx.x * 16;
    unsigned short* o = out + m * 16384 + part * 4096 + threadIdx.x * 16;
    float f[16];
#pragma unroll
    for (int i = 0; i < 4; ++i) *(f32x4*)(f + 4 * i) = ((const f32x4*)w)[i];
    unsigned short tmp[16];
#pragma unroll
    for (int i = 0; i < 16; ++i) tmp[i] = f2bf(f[i]);
    ((u16x8*)o)[0] = *(u16x8*)tmp;
    ((u16x8*)o)[1] = *(u16x8*)(tmp + 8);
}

// ================= sort: hist -> 3-kernel scan -> position =================
__global__ void k_hist(const int* __restrict__ dst, int* __restrict__ cnt) {
    int i = blockIdx.x * 256 + threadIdx.x;
    if (i < NE) atomicAdd(&cnt[dst[i]], 1);
}

__global__ void k_scan1(const int* __restrict__ c, int* __restrict__ bsum) {
    __shared__ int red[256];
    int i = blockIdx.x * 256 + threadIdx.x;
    red[threadIdx.x] = (i < NN) ? c[i] : 0;
    __syncthreads();
    for (int off = 128; off > 0; off >>= 1) {
        if (threadIdx.x < off) red[threadIdx.x] += red[threadIdx.x + off];
        __syncthreads();
    }
    if (threadIdx.x == 0) bsum[blockIdx.x] = red[0];
}

__global__ void k_scan2(int* __restrict__ bsum) {   // 1 block, 256 threads
    __shared__ int s[256];
    int t = threadIdx.x;
    s[t] = (t < NBLK_SCAN) ? bsum[t] : 0;
    __syncthreads();
    for (int off = 1; off < 256; off <<= 1) {
        int v = (t >= off) ? s[t - off] : 0;
        __syncthreads();
        s[t] += v;
        __syncthreads();
    }
    if (t < NBLK_SCAN) bsum[t] = (t == 0) ? 0 : s[t - 1];
}

__global__ void k_scan3(int* __restrict__ cnt, const int* __restrict__ bsum,
                        int* __restrict__ rowptr) {
    __shared__ int s[256];
    int t = threadIdx.x;
    int i = blockIdx.x * 256 + t;
    int v = (i < NN) ? cnt[i] : 0;
    s[t] = v;
    __syncthreads();
    for (int off = 1; off < 256; off <<= 1) {
        int x = (t >= off) ? s[t - off] : 0;
        __syncthreads();
        s[t] += x;
        __syncthreads();
    }
    int excl = bsum[blockIdx.x] + s[t] - v;
    if (i < NN) { rowptr[i] = excl; cnt[i] = excl; }   // cnt becomes cursor
    if (i == 0) rowptr[NN] = NE;
}

__global__ void k_pos(const int* __restrict__ dst, int* __restrict__ cursor,
                      int* __restrict__ pos) {
    int i = blockIdx.x * 256 + threadIdx.x;
    if (i < NE) pos[i] = atomicAdd(&cursor[dst[i]], 1);
}

// ================= node pre: AH = [Asrc row | Hb row], Adst =================
__global__ __launch_bounds__(256, 3)
void k_nodepre(const float* __restrict__ h,
               const unsigned short* __restrict__ Wb,
               const float* __restrict__ bsrc, const float* __restrict__ bdst,
               unsigned short* __restrict__ AH, unsigned short* __restrict__ Adst) {
    __shared__ unsigned short X[64 * 136];
    int tid = threadIdx.x, lane = tid & 63, wv = tid >> 6;
    int n0 = blockIdx.x * 64;
    {
        int row = tid >> 2, q = tid & 3;
        int n = n0 + row;
        if (n < NN) {
            unsigned short tmp[32];
            const f32x4* hp = (const f32x4*)(h + (size_t)n * 128 + q * 32);
#pragma unroll
            for (int i = 0; i < 8; ++i) {
                f32x4 v = hp[i];
#pragma unroll
                for (int j = 0; j < 4; ++j) tmp[i * 4 + j] = f2bf(v[j]);
            }
#pragma unroll
            for (int i = 0; i < 4; ++i)
                *(u16x8*)(X + row * 136 + q * 32 + i * 8) = *(u16x8*)(tmp + i * 8);
            u16x8* hb = (u16x8*)(AH + (size_t)n * 256 + 128 + q * 32);
#pragma unroll
            for (int i = 0; i < 4; ++i) hb[i] = *(u16x8*)(tmp + i * 8);
        } else {
            u16x8 z = {0, 0, 0, 0, 0, 0, 0, 0};
#pragma unroll
            for (int i = 0; i < 4; ++i) *(u16x8*)(X + row * 136 + q * 32 + i * 8) = z;
        }
    }
    __syncthreads();

    bf16x8 wfS[4][2], wfD[4][2];
    load_wfrags(Wb, wv, lane, wfS);
    load_wfrags(Wb + 16384, wv, lane, wfD);
    f32x4 accS[4][2], accD[4][2];
    zero_acc(accS); zero_acc(accD);
    gemm64(X, wfS, accS, lane);
    gemm64(X, wfD, accD, lane);

    int c0 = 32 * wv + (lane & 15);
    float bs0 = bsrc[c0], bs1 = bsrc[c0 + 16];
    float bd0 = bdst[c0], bd1 = bdst[c0 + 16];
    int rbase = (lane >> 4) * 4;
#pragma unroll
    for (int mt = 0; mt < 4; ++mt)
#pragma unroll
        for (int r = 0; r < 4; ++r) {
            int n = n0 + mt * 16 + rbase + r;
            if (n < NN) {
                AH[(size_t)n * 256 + c0]        = f2bf(accS[mt][0][r] + bs0);
                AH[(size_t)n * 256 + c0 + 16]   = f2bf(accS[mt][1][r] + bs1);
                Adst[(size_t)n * 128 + c0]      = f2bf(accD[mt][0][r] + bd0);
                Adst[(size_t)n * 128 + c0 + 16] = f2bf(accD[mt][1][r] + bd1);
            }
        }
}

// ===== edge MLP: 3 W-sets resident, Hs in LDS (53KB, 3blk/CU), idx+ef prefetch
__global__ __launch_bounds__(256, 3)
void k_edgeB(const float* __restrict__ ef,
             const int* __restrict__ src, const int* __restrict__ dst,
             const int* __restrict__ pos,
             const unsigned short* __restrict__ AH,
             const unsigned short* __restrict__ Adst,
             const unsigned short* __restrict__ Wb,
             const float* __restrict__ b1, const float* __restrict__ b2,
             const float* __restrict__ b3,
             unsigned short* __restrict__ Mbuf) {
    __shared__ __align__(16) char sh[52480];
    unsigned short* X0 = (unsigned short*)sh;             // [64][136]
    unsigned short* X1 = (unsigned short*)(sh + 17408);   // [64][136]
    unsigned short* Hs = (unsigned short*)(sh + 34816);   // [64][136]
    int*         posarr = (int*)(sh + 52224);             // [64]

    int tid = threadIdx.x, lane = tid & 63, wv = tid >> 6;

    // ALL THREE weight sets resident; Hs in LDS frees the 16 hbr VGPRs so
    // {wf×3 + efr prefetch} fits the (256,3) budget (R4 base 84 + 32 + 32 ≈ 150).
    bf16x8 wf1[4][2], wf2[4][2], wf3[4][2];
    load_wfrags(Wb + 2 * 16384, wv, lane, wf1);   // Wphi1
    load_wfrags(Wb + 3 * 16384, wv, lane, wf2);   // Wphi2
    load_wfrags(Wb + 4 * 16384, wv, lane, wf3);   // Wphi3

    int c0 = 32 * wv + (lane & 15);
    float b1_0 = b1[c0], b1_1 = b1[c0 + 16];
    float b2_0 = b2[c0], b2_1 = b2[c0 + 16];
    float b3_0 = b3[c0], b3_1 = b3[c0 + 16];
    int rbase = (lane >> 4) * 4;
    int srow = tid >> 2, q = tid & 3;

    // contiguous chunk per block: ef stream stays sequential per block
    int b = blockIdx.x, nb = gridDim.x;
    int qt = NT_E / nb, rt = NT_E % nb;
    int t0 = (b < rt) ? b * (qt + 1) : rt * (qt + 1) + (b - rt) * qt;
    int t1 = t0 + ((b < rt) ? qt + 1 : qt);

    // prefetch state: indices (3 sgpr-ish regs) + ef rows (8 f32x4 = 32 VGPR)
    int sN, dN, pN;
    f32x4 efr[8];
    {
        int e = t0 * 64 + srow;
        sN = src[e]; dN = dst[e]; pN = pos[e];
        const f32x4* ep = (const f32x4*)(ef + (size_t)e * 128 + q * 32);
#pragma unroll
        for (int i = 0; i < 8; ++i) efr[i] = ep[i];
    }

    for (int t = t0; t < t1; ++t) {
        int s = sN, d = dN, p = pN;
        syncl();                               // prev store-phase LDS reads done
        {   // stage: X0 = relu(efr + AH.a[src] + Adst[dst]); Hs = AH.h[src]
            if (q == 0) posarr[srow] = p;
            const u16x8* ap = (const u16x8*)(AH + (size_t)s * 256 + q * 32);
            const u16x8* hp = (const u16x8*)(AH + (size_t)s * 256 + 128 + q * 32);
            const u16x8* dp = (const u16x8*)(Adst + (size_t)d * 128 + q * 32);
#pragma unroll
            for (int i = 0; i < 4; ++i) {
                u16x8 a8 = ap[i], d8 = dp[i], h8 = hp[i];
                f32x4 lo = efr[2 * i], hi = efr[2 * i + 1];
                unsigned short o[8];
#pragma unroll
                for (int j = 0; j < 8; ++j) {
                    float evv = (j < 4) ? lo[j] : hi[j - 4];
                    float v = evv + bf2f((unsigned short)a8[j]) + bf2f((unsigned short)d8[j]);
                    o[j] = f2bf(fmaxf(v, 0.f));
                }
                *(u16x8*)(X0 + srow * 136 + q * 32 + i * 8) = *(u16x8*)o;
                *(u16x8*)(Hs + srow * 136 + q * 32 + i * 8) = h8;
            }
        }
        if (t + 1 < t1) {                      // issue next-tile idx + ef loads;
            int e = (t + 1) * 64 + srow;       // they land during the GEMM phases
            sN = src[e]; dN = dst[e]; pN = pos[e];
            const f32x4* ep = (const f32x4*)(ef + (size_t)e * 128 + q * 32);
#pragma unroll
            for (int i = 0; i < 8; ++i) efr[i] = ep[i];
        }
        syncl();                               // X0/Hs/posarr visible
        f32x4 acc[4][2];
        zero_acc(acc);
        gemm64(X0, wf1, acc, lane);
        syncl();                               // X0 reads done
        epi_lds(X1, acc, b1_0, b1_1, c0, rbase);
        syncl();                               // X1 ready
        zero_acc(acc);
        gemm64(X1, wf2, acc, lane);
        epi_lds(X0, acc, b2_0, b2_1, c0, rbase);
        syncl();                               // X0 ready (X1 reads also done)
        zero_acc(acc);
        gemm64(X0, wf3, acc, lane);
        syncl();                               // X1 free (gemm2 reads long done)
        epi_lds_norelu(X1, acc, b3_0, b3_1, c0, rbase);  // X1 = e_emb + b3 (bf16)
        syncl();                               // X1 ready
        // m = Hs * e_emb in staging layout; 64B store per thread to Mbuf
        {
            int posr = posarr[srow];
            unsigned short* mp = Mbuf + (size_t)posr * 128 + q * 32;
#pragma unroll
            for (int i = 0; i < 4; ++i) {
                u16x8 ev = *(const u16x8*)(X1 + srow * 136 + q * 32 + i * 8);
                u16x8 hv = *(const u16x8*)(Hs + srow * 136 + q * 32 + i * 8);
                u16x8 o;
#pragma unroll
                for (int j = 0; j < 8; ++j)
                    o[j] = f2bf(bf2f((unsigned short)ev[j]) * bf2f((unsigned short)hv[j]));
                *(u16x8*)(mp + i * 8) = o;
            }
        }
    }
}

// ===== fused aggregate + node output (primary path) =====
__global__ __launch_bounds__(256, 3)
void k_nodeoutF(const unsigned short* __restrict__ AH,
                const unsigned short* __restrict__ Mbuf,
                const int* __restrict__ rowptr,
                const unsigned short* __restrict__ Wb,
                const float* __restrict__ bpd, const float* __restrict__ bpu,
                const float* __restrict__ bt1, const float* __restrict__ bt2,
                float* __restrict__ out) {
    __shared__ unsigned short Xh[64 * 136];
    __shared__ unsigned short Xa[64 * 136];
    int tid = threadIdx.x, lane = tid & 63, wv = tid >> 6;
    int n0 = blockIdx.x * 64;
    {   // stage Xh = AH.h
        int row = tid >> 2, q = tid & 3;
        int n = n0 + row;
        if (n < NN) {
            const u16x8* hp = (const u16x8*)(AH + (size_t)n * 256 + 128 + q * 32);
#pragma unroll
            for (int i = 0; i < 4; ++i)
                *(u16x8*)(Xh + row * 136 + q * 32 + i * 8) = hp[i];
        } else {
            u16x8 z = {0, 0, 0, 0, 0, 0, 0, 0};
#pragma unroll
            for (int i = 0; i < 4; ++i)
                *(u16x8*)(Xh + row * 136 + q * 32 + i * 8) = z;
        }
    }
    {   // fused agg: one node per wave-iteration, sequential Mbuf rows
#pragma unroll 1
        for (int it = 0; it < 16; ++it) {
            int row = wv * 16 + it;
            int n = n0 + row;
            float a0 = 0.f, a1 = 0.f;
            if (n < NN) {
                int j0 = rowptr[n], j1 = rowptr[n + 1];
                int j = j0;
                for (; j + 3 < j1; j += 4) {
                    u16x2 v0 = *(const u16x2*)(Mbuf + (size_t)j * 128 + lane * 2);
                    u16x2 v1 = *(const u16x2*)(Mbuf + (size_t)(j + 1) * 128 + lane * 2);
                    u16x2 v2 = *(const u16x2*)(Mbuf + (size_t)(j + 2) * 128 + lane * 2);
                    u16x2 v3 = *(const u16x2*)(Mbuf + (size_t)(j + 3) * 128 + lane * 2);
                    a0 += bf2f(v0[0]) + bf2f(v1[0]) + bf2f(v2[0]) + bf2f(v3[0]);
                    a1 += bf2f(v0[1]) + bf2f(v1[1]) + bf2f(v2[1]) + bf2f(v3[1]);
                }
                for (; j < j1; ++j) {
                    u16x2 v = *(const u16x2*)(Mbuf + (size_t)j * 128 + lane * 2);
                    a0 += bf2f(v[0]); a1 += bf2f(v[1]);
                }
            }
            Xa[row * 136 + lane * 2]     = f2bf(a0);
            Xa[row * 136 + lane * 2 + 1] = f2bf(a1);
        }
    }
    __syncthreads();
    bf16x8 wfa[4][2], wfb[4][2];
    load_wfrags(Wb + 5 * 16384, wv, lane, wfa);   // Wpd
    load_wfrags(Wb + 6 * 16384, wv, lane, wfb);   // Wpu
    int c0 = 32 * wv + (lane & 15);
    int rbase = (lane >> 4) * 4;
    f32x4 acc[4][2];
    zero_acc(acc);
    gemm64(Xh, wfa, acc, lane);
    gemm64(Xa, wfb, acc, lane);
    float bb0 = bpd[c0] + bpu[c0], bb1 = bpd[c0 + 16] + bpu[c0 + 16];
    __syncthreads();
    epi_lds(Xh, acc, bb0, bb1, c0, rbase);
    __syncthreads();
    load_wfrags(Wb + 7 * 16384, wv, lane, wfa);   // Wth1
    zero_acc(acc);
    gemm64(Xh, wfa, acc, lane);
    float b10 = bt1[c0], b11 = bt1[c0 + 16];
    __syncthreads();
    epi_lds(Xa, acc, b10, b11, c0, rbase);
    __syncthreads();
    load_wfrags(Wb + 8 * 16384, wv, lane, wfb);   // Wth2
    zero_acc(acc);
    gemm64(Xa, wfb, acc, lane);
    float b20 = bt2[c0], b21 = bt2[c0 + 16];
#pragma unroll
    for (int mt = 0; mt < 4; ++mt)
#pragma unroll
        for (int r = 0; r < 4; ++r) {
            int n = n0 + mt * 16 + rbase + r;
            if (n < NN) {
                out[(size_t)n * 128 + c0]      = acc[mt][0][r] + b20;
                out[(size_t)n * 128 + c0 + 16] = acc[mt][1][r] + b21;
            }
        }
}

// ============ fallback edge kernel (direct atomics, small-ws path) ============
__global__ __launch_bounds__(256, 2)
void k_edge_atomic(const float* __restrict__ ef,
                   const int* __restrict__ src, const int* __restrict__ dst,
                   const unsigned short* __restrict__ AH,
                   const unsigned short* __restrict__ Adst,
                   const unsigned short* __restrict__ Wb,
                   const float* __restrict__ b1, const float* __restrict__ b2,
                   const float* __restrict__ b3,
                   float* __restrict__ agg) {
    __shared__ unsigned short X0[64 * 136];
    __shared__ unsigned short X1[64 * 136];
    __shared__ unsigned short Hs[64 * 136];
    __shared__ int doff_lds[64];

    int tid = threadIdx.x, lane = tid & 63, wv = tid >> 6;
    bf16x8 wf1[4][2], wf2[4][2], wf3[4][2];
    load_wfrags(Wb + 2 * 16384, wv, lane, wf1);
    load_wfrags(Wb + 3 * 16384, wv, lane, wf2);
    load_wfrags(Wb + 4 * 16384, wv, lane, wf3);

    int c0 = 32 * wv + (lane & 15);
    float b1_0 = b1[c0], b1_1 = b1[c0 + 16];
    float b2_0 = b2[c0], b2_1 = b2[c0 + 16];
    float b3_0 = b3[c0], b3_1 = b3[c0 + 16];
    int rbase = (lane >> 4) * 4;
    int srow = tid >> 2, q = tid & 3;

    for (int t = blockIdx.x; t < NT_E; t += gridDim.x) {
        int e0 = t * 64;
        __syncthreads();
        {
            int e = e0 + srow;
            int s = src[e], d = dst[e];
            if (q == 0) doff_lds[srow] = d * 128;
            const f32x4* ep = (const f32x4*)(ef + (size_t)e * 128 + q * 32);
            const u16x8* ap = (const u16x8*)(AH + (size_t)s * 256 + q * 32);
            const u16x8* hp = (const u16x8*)(AH + (size_t)s * 256 + 128 + q * 32);
            const u16x8* dp = (const u16x8*)(Adst + (size_t)d * 128 + q * 32);
#pragma unroll
            for (int i = 0; i < 4; ++i) {
                u16x8 a8 = ap[i], d8 = dp[i], h8 = hp[i];
                f32x4 lo = ep[2 * i], hi = ep[2 * i + 1];
                unsigned short o[8];
#pragma unroll
                for (int j = 0; j < 8; ++j) {
                    float evv = (j < 4) ? lo[j] : hi[j - 4];
                    float v = evv + bf2f((unsigned short)a8[j]) + bf2f((unsigned short)d8[j]);
                    o[j] = f2bf(fmaxf(v, 0.f));
                }
                *(u16x8*)(X0 + srow * 136 + q * 32 + i * 8) = *(u16x8*)o;
                *(u16x8*)(Hs + srow * 136 + q * 32 + i * 8) = h8;
            }
        }
        __syncthreads();
        f32x4 acc[4][2];
        zero_acc(acc);
        gemm64(X0, wf1, acc, lane);
        __syncthreads();
        epi_lds(X1, acc, b1_0, b1_1, c0, rbase);
        __syncthreads();
        zero_acc(acc);
        gemm64(X1, wf2, acc, lane);
        epi_lds(X0, acc, b2_0, b2_1, c0, rbase);
        __syncthreads();
        zero_acc(acc);
        gemm64(X0, wf3, acc, lane);
#pragma unroll
        for (int mt = 0; mt < 4; ++mt)
#pragma unroll
            for (int r = 0; r < 4; ++r) {
                int row = mt * 16 + rbase + r;
                int dofs = doff_lds[row];
                float h0 = bf2f(Hs[row * 136 + c0]);
                float h1 = bf2f(Hs[row * 136 + c0 + 16]);
                atomicAdd(agg + dofs + c0,      (acc[mt][0][r] + b3_0) * h0);
                atomicAdd(agg + dofs + c0 + 16, (acc[mt][1][r] + b3_1) * h1);
            }
    }
}

// ================= node output (fallback path: reads agg f32) =================
__global__ __launch_bounds__(256, 3)
void k_nodeout(const unsigned short* __restrict__ AH,
               const float* __restrict__ agg,
               const unsigned short* __restrict__ Wb,
               const float* __restrict__ bpd, const float* __restrict__ bpu,
               const float* __restrict__ bt1, const float* __restrict__ bt2,
               float* __restrict__ out) {
    __shared__ unsigned short Xh[64 * 136];
    __shared__ unsigned short Xa[64 * 136];
    int tid = threadIdx.x, lane = tid & 63, wv = tid >> 6;
    int n0 = blockIdx.x * 64;
    {
        int row = tid >> 2, q = tid & 3;
        int n = n0 + row;
        if (n < NN) {
            const u16x8* hp = (const u16x8*)(AH + (size_t)n * 256 + 128 + q * 32);
#pragma unroll
            for (int i = 0; i < 4; ++i)
                *(u16x8*)(Xh + row * 136 + q * 32 + i * 8) = hp[i];
            stage_f32row(Xa + row * 136 + q * 32,
                         (const f32x4*)(agg + (size_t)n * 128 + q * 32));
        } else {
            u16x8 z = {0, 0, 0, 0, 0, 0, 0, 0};
#pragma unroll
            for (int i = 0; i < 4; ++i) {
                *(u16x8*)(Xh + row * 136 + q * 32 + i * 8) = z;
                *(u16x8*)(Xa + row * 136 + q * 32 + i * 8) = z;
            }
        }
    }
    __syncthreads();
    bf16x8 wfa[4][2], wfb[4][2];
    load_wfrags(Wb + 5 * 16384, wv, lane, wfa);
    load_wfrags(Wb + 6 * 16384, wv, lane, wfb);
    int c0 = 32 * wv + (lane & 15);
    int rbase = (lane >> 4) * 4;
    f32x4 acc[4][2];
    zero_acc(acc);
    gemm64(Xh, wfa, acc, lane);
    gemm64(Xa, wfb, acc, lane);
    float bb0 = bpd[c0] + bpu[c0], bb1 = bpd[c0 + 16] + bpu[c0 + 16];
    __syncthreads();
    epi_lds(Xh, acc, bb0, bb1, c0, rbase);
    __syncthreads();
    load_wfrags(Wb + 7 * 16384, wv, lane, wfa);
    zero_acc(acc);
    gemm64(Xh, wfa, acc, lane);
    float b10 = bt1[c0], b11 = bt1[c0 + 16];
    __syncthreads();
    epi_lds(Xa, acc, b10, b11, c0, rbase);
    __syncthreads();
    load_wfrags(Wb + 8 * 16384, wv, lane, wfb);
    zero_acc(acc);
    gemm64(Xa, wfb, acc, lane);
    float b20 = bt2[c0], b21 = bt2[c0 + 16];
#pragma unroll
    for (int mt = 0; mt < 4; ++mt)
#pragma unroll
        for (int r = 0; r < 4; ++r) {
            int n = n0 + mt * 16 + rbase + r;
            if (n < NN) {
                out[(size_t)n * 128 + c0]      = acc[mt][0][r] + b20;
                out[(size_t)n * 128 + c0 + 16] = acc[mt][1][r] + b21;
            }
        }
}

extern "C" void kernel_launch(void* const* d_in, const int* in_sizes, int n_in,
                              void* d_out, int out_size, void* d_ws, size_t ws_size,
                              hipStream_t stream) {
    (void)in_sizes; (void)n_in; (void)out_size;
    const float* node_feat = (const float*)d_in[0];
    const float* edge_feat = (const float*)d_in[1];
    const int*   src  = (const int*)d_in[2];
    const int*   dst  = (const int*)d_in[3];
    const float* Wsrc = (const float*)d_in[4];  const float* bsrc = (const float*)d_in[5];
    const float* Wdst = (const float*)d_in[6];  const float* bdst = (const float*)d_in[7];
    const float* Wphi1 = (const float*)d_in[8]; const float* bphi1 = (const float*)d_in[9];
    const float* Wphi2 = (const float*)d_in[10];const float* bphi2 = (const float*)d_in[11];
    const float* Wphi3 = (const float*)d_in[12];const float* bphi3 = (const float*)d_in[13];
    const float* Wth1 = (const float*)d_in[14]; const float* bth1 = (const float*)d_in[15];
    const float* Wth2 = (const float*)d_in[16]; const float* bth2 = (const float*)d_in[17];
    const float* Wpd  = (const float*)d_in[18]; const float* bpd  = (const float*)d_in[19];
    const float* Wpu  = (const float*)d_in[20]; const float* bpu  = (const float*)d_in[21];

    // workspace carve (~272.6 MB primary)
    char* ws = (char*)d_ws;
    size_t off = 0;
    unsigned short* Wb   = (unsigned short*)(ws + off); off += 294912;
    unsigned short* AH   = (unsigned short*)(ws + off); off += 25600000;   // [Asrc|Hb]
    unsigned short* Adst = (unsigned short*)(ws + off); off += 12800000;
    float*          agg  = (float*)(ws + off);          off += 25600000;
    int*            cnt  = (int*)(ws + off);            off += 200064;
    int*            rowptr = (int*)(ws + off);          off += 200064;
    int*            bsum = (int*)(ws + off);            off += 1024;
    int*            pos  = (int*)(ws + off);            off += 3200000;
    unsigned short* Mbuf = (unsigned short*)(ws + off); off += 204800000;
    bool primary = (ws_size >= off);

    k_wconv<<<36, 256, 0, stream>>>(Wsrc, Wdst, Wphi1, Wphi2, Wphi3,
                                    Wpd, Wpu, Wth1, Wth2, Wb);
    k_nodepre<<<782, 256, 0, stream>>>(node_feat, Wb, bsrc, bdst, AH, Adst);

    if (primary) {
        hipMemsetAsync(cnt, 0, (size_t)NN * 4, stream);
        k_hist<<<3125, 256, 0, stream>>>(dst, cnt);
        k_scan1<<<NBLK_SCAN, 256, 0, stream>>>(cnt, bsum);
        k_scan2<<<1, 256, 0, stream>>>(bsum);
        k_scan3<<<NBLK_SCAN, 256, 0, stream>>>(cnt, bsum, rowptr);
        k_pos<<<3125, 256, 0, stream>>>(dst, cnt, pos);
        k_edgeB<<<GRID_E, 256, 0, stream>>>(edge_feat, src, dst, pos,
                                            AH, Adst, Wb,
                                            bphi1, bphi2, bphi3, Mbuf);
        k_nodeoutF<<<782, 256, 0, stream>>>(AH, Mbuf, rowptr, Wb,
                                            bpd, bpu, bth1, bth2, (float*)d_out);
    } else {
        hipMemsetAsync(agg, 0, (size_t)NN * 128 * 4, stream);
        k_edge_atomic<<<1024, 256, 0, stream>>>(edge_feat, src, dst,
                                                AH, Adst, Wb,
                                                bphi1, bphi2, bphi3, agg);
        k_nodeout<<<782, 256, 0, stream>>>(AH, agg, Wb, bpd, bpu, bth1, bth2,
                                           (float*)d_out);
    }
}